// Round 7
// baseline (144.780 us; speedup 1.0000x reference)
//
#include <hip/hip_runtime.h>
#include <hip/hip_bf16.h>

// Problem constants
#define L_DIM 128
#define N_DIM 32
#define C_DIM 128
#define K_DIM 128   // DIM_MLP
#define OUT_DIM 128

typedef __attribute__((ext_vector_type(8))) short short8;
typedef __attribute__((ext_vector_type(4))) float float4v;

static __device__ __forceinline__ short bf16_bits(float f) {
    __bf16 h = (__bf16)f;   // RNE
    return __builtin_bit_cast(short, h);
}

// async global->LDS, 16 B per lane, dest = wave-uniform base + lane*16
static __device__ __forceinline__ void gl_lds16(const float* g, float* l) {
    __builtin_amdgcn_global_load_lds(
        (const __attribute__((address_space(1))) unsigned int*)g,
        (__attribute__((address_space(3))) unsigned int*)l, 16, 0, 0);
}

// ---------------------------------------------------------------------------
// Kernel 1: precompute. 16 rows/block (halves L2 weight re-read traffic
//   vs 8 rows: 512->256 weight-set reads of 256 KB).
//   blocks 0..255  : b = bid>>3, i0 = (bid&7)*16.  P = x·W1a ; Q = x·W1b+b1 ;
//                    Vt[b][c][i] = relu(x·Vw1+vb1)·Vw2 + vb2 (transposed)
//   blocks 256..319: W2s = attn_w2 swizzled into bf16 MFMA B-fragment order
// ---------------------------------------------------------------------------
__global__ __launch_bounds__(256) void k_pre(
    const float* __restrict__ x,
    const float* __restrict__ attn_w1, const float* __restrict__ attn_b1,
    const float* __restrict__ attn_w2,
    const float* __restrict__ value_w1, const float* __restrict__ value_b1,
    const float* __restrict__ value_w2, const float* __restrict__ value_b2,
    float* __restrict__ P, float* __restrict__ Q, float* __restrict__ Vt,
    short* __restrict__ W2s)
{
    int bid = blockIdx.x;
    if (bid >= 256) {
        // W2 swizzle: element e = ((((ct*4+mi)*4+quad)*16+col)*8+idx)
        int e = (bid - 256) * 256 + threadIdx.x;      // 64*256 = 16384 elems
        int idx  = e & 7;
        int colr = (e >> 3) & 15;
        int quad = (e >> 7) & 3;
        int mi   = (e >> 9) & 3;
        int ct   = e >> 11;
        int k = quad * 8 + 32 * mi + idx;
        int c = ct * 16 + colr;
        W2s[e] = bf16_bits(attn_w2[k * OUT_DIM + c]);
        return;
    }

    __shared__ float xs[16][C_DIM];
    __shared__ float hvs[16][K_DIM];
    int tid = threadIdx.x;
    int b   = bid >> 3;             // batch (same for all 16 rows)
    int i0g = (bid & 7) * 16;       // first i

    {   // cooperative load of 16 x-rows (2048 floats, 8 per thread)
        int f = tid * 8;
        int row = f >> 7, c = f & 127;
        const float* xp = x + ((size_t)(i0g + row) * N_DIM + b) * C_DIM + c;
        *(float4v*)(&xs[row][c])     = *(const float4v*)xp;
        *(float4v*)(&xs[row][c + 4]) = *(const float4v*)(xp + 4);
    }
    __syncthreads();

    int ks   = tid & 127;      // output column k (or c)
    int half = tid >> 7;       // rows 0-7 vs 8-15

    float pacc[8] = {0,0,0,0,0,0,0,0};
    float qacc[8] = {0,0,0,0,0,0,0,0};
    float hacc[8] = {0,0,0,0,0,0,0,0};
    #pragma unroll 4
    for (int c = 0; c < C_DIM; ++c) {
        float wa = attn_w1[c * K_DIM + ks];
        float wb = attn_w1[(C_DIM + c) * K_DIM + ks];
        float wv = value_w1[c * K_DIM + ks];
        #pragma unroll
        for (int r = 0; r < 8; ++r) {
            float xr = xs[half * 8 + r][c];
            pacc[r] = fmaf(xr, wa, pacc[r]);
            qacc[r] = fmaf(xr, wb, qacc[r]);
            hacc[r] = fmaf(xr, wv, hacc[r]);
        }
    }
    float b1 = attn_b1[ks], vb1 = value_b1[ks];
    #pragma unroll
    for (int r = 0; r < 8; ++r) {
        int i = i0g + half * 8 + r;
        P[((size_t)b * L_DIM + i) * K_DIM + ks] = pacc[r];
        Q[((size_t)b * L_DIM + i) * K_DIM + ks] = qacc[r] + b1;
        hvs[half * 8 + r][ks] = fmaxf(hacc[r] + vb1, 0.f);
    }
    __syncthreads();

    float vacc[8] = {0,0,0,0,0,0,0,0};
    #pragma unroll 4
    for (int k = 0; k < K_DIM; ++k) {
        float w = value_w2[k * OUT_DIM + ks];
        #pragma unroll
        for (int r = 0; r < 8; ++r)
            vacc[r] = fmaf(hvs[half * 8 + r][k], w, vacc[r]);
    }
    float vb2 = value_b2[ks];
    // transposed store: Vt[b][c=ks][j = i0g+half*8 .. +7] -- two float4
    float* vp = Vt + ((size_t)b * OUT_DIM + ks) * L_DIM + i0g + half * 8;
    float4v v0 = { vacc[0] + vb2, vacc[1] + vb2, vacc[2] + vb2, vacc[3] + vb2 };
    float4v v1 = { vacc[4] + vb2, vacc[5] + vb2, vacc[6] + vb2, vacc[7] + vb2 };
    *(float4v*)vp       = v0;
    *(float4v*)(vp + 4) = v1;
}

// ---------------------------------------------------------------------------
// Kernel 2: fused pairwise-MLP + j-reduce.  BARRIER-FREE edition.
//   Post-mortem r3-r6: every barrier variant returned ~0 — __syncthreads on
//   gfx950 drains vmcnt(0), so all "prefetch" completed inside its own round
//   and the schedule stayed load->drain->compute in lockstep. This version
//   has ZERO barriers in the main loop: Q/V are read straight from L1/L2
//   into registers (working set per b: 64KB Q + 64KB Vt, cache-resident;
//   4 waves/block re-read the same Q tile -> 3/4 are L1 hits). Q is
//   register-pipelined 2 deep (static parity under full unroll). Waves run
//   fully independent; compiler schedules with counted vmcnt, not drains.
//   block = (b, it4 of 4 i's); 4 waves = 2 ipair x 2 cth (verified layout).
// ---------------------------------------------------------------------------
__global__ __launch_bounds__(256)
__attribute__((amdgpu_waves_per_eu(2)))
void k_main(
    const float* __restrict__ P, const float* __restrict__ Q,
    const float* __restrict__ Vt,
    const short* __restrict__ W2s, const float* __restrict__ attn_b2,
    float* __restrict__ out)
{
    __shared__ float P_lds[512];    // 4 i-rows; only LDS left (2 KB)

    int b    = blockIdx.x >> 5;
    int it4  = blockIdx.x & 31;
    int tid  = threadIdx.x;
    int wave = tid >> 6;
    int lane = tid & 63;
    int quad = lane >> 4;
    int col  = lane & 15;
    int ip   = wave >> 1;           // which i-pair
    int cth  = wave & 1;            // ct half: tiles cth*4 .. cth*4+3

    // B fragments: 4 ct tiles (verified swizzle, unchanged)
    short8 bfrag[4][4];
    const short8* w2p = (const short8*)W2s;
    #pragma unroll
    for (int cl = 0; cl < 4; ++cl)
        #pragma unroll
        for (int mi = 0; mi < 4; ++mi)
            bfrag[cl][mi] =
                w2p[(((cth * 4 + cl) * 4 + mi) * 4 + quad) * 16 + col];

    // P tile -> LDS once (DMA), single barrier of the kernel
    if (wave == 0) {
        const float* Pbase = P + ((size_t)b * L_DIM + it4 * 4) * K_DIM;
        gl_lds16(Pbase + lane * 4,       &P_lds[0]);
        gl_lds16(Pbase + 256 + lane * 4, &P_lds[256]);
    }
    __syncthreads();

    // per-lane global bases
    // Q[j][k]: lane reads j = jt*16+col, k = ksl*32 + quad*8 + t
    const float* qa = Q  + (size_t)b * L_DIM * K_DIM + col * K_DIM + quad * 8;
    // Vt[c][j]: lane reads c = cth*64+cl*16+col, j = jt*16 + quad*4 ..+3
    const float* va = Vt + (size_t)b * OUT_DIM * L_DIM
                         + (cth * 64 + col) * L_DIM + quad * 4;

    float acc0[4] = {0.f, 0.f, 0.f, 0.f};
    float acc1[4] = {0.f, 0.f, 0.f, 0.f};
    float sv[4]   = {0.f, 0.f, 0.f, 0.f};
    int pofs = 0;      // opaque 0: keeps P reads in LDS (blocks reg-hoist)

    // Q register pipeline, 2 rounds deep: qreg[parity][ksl][half]
    float4v qreg[2][4][2];
    #pragma unroll
    for (int ksl = 0; ksl < 4; ++ksl) {
        qreg[0][ksl][0] = *(const float4v*)(qa + ksl * 32);
        qreg[0][ksl][1] = *(const float4v*)(qa + ksl * 32 + 4);
    }

    #pragma unroll
    for (int r = 0; r < 8; ++r) {
        asm volatile("" : "+v"(pofs));

        // ---- V(r) loads (latency hides under build+MFMA below) ----
        float4v vv[4];
        #pragma unroll
        for (int cl = 0; cl < 4; ++cl)
            vv[cl] = *(const float4v*)(va + (size_t)cl * 16 * L_DIM + r * 16);

        // ---- Q(r+1) loads into other parity (no barrier: free to fly) ----
        if (r < 7) {
            const float* qn = qa + (r + 1) * 16 * K_DIM;
            #pragma unroll
            for (int ksl = 0; ksl < 4; ++ksl) {
                qreg[(r + 1) & 1][ksl][0] = *(const float4v*)(qn + ksl * 32);
                qreg[(r + 1) & 1][ksl][1] = *(const float4v*)(qn + ksl * 32 + 4);
            }
        }

        // ---- build af(r) from qreg[r&1] + P_lds broadcast ----
        short8 af[2][4];
        const float* Pr = &P_lds[(ip * 2) * 128 + quad * 8 + pofs];
        #pragma unroll
        for (int ksl = 0; ksl < 4; ++ksl) {
            float4v q0 = qreg[r & 1][ksl][0];
            float4v q1 = qreg[r & 1][ksl][1];
            #pragma unroll
            for (int ii = 0; ii < 2; ++ii) {
                const float* Pc = Pr + ii * 128 + ksl * 32;
                float4v s0 = *(const float4v*)Pc + q0;
                float4v s1 = *(const float4v*)(Pc + 4) + q1;
                short8 a;
                #pragma unroll
                for (int t = 0; t < 4; ++t) {
                    a[t]     = bf16_bits(fmaxf(s0[t], 0.f));
                    a[t + 4] = bf16_bits(fmaxf(s1[t], 0.f));
                }
                af[ii][ksl] = a;
            }
        }

        // ---- MFMA(r) + V-scale + fused Sv ----
        #pragma unroll
        for (int cl = 0; cl < 4; ++cl) {
            float4v c40 = {0.f, 0.f, 0.f, 0.f};
            float4v c41 = {0.f, 0.f, 0.f, 0.f};
            #pragma unroll
            for (int ksl = 0; ksl < 4; ++ksl) {
                c40 = __builtin_amdgcn_mfma_f32_16x16x32_bf16(
                        af[0][ksl], bfrag[cl][ksl], c40, 0, 0, 0);
                c41 = __builtin_amdgcn_mfma_f32_16x16x32_bf16(
                        af[1][ksl], bfrag[cl][ksl], c41, 0, 0, 0);
            }
            #pragma unroll
            for (int rr = 0; rr < 4; ++rr) {
                acc0[cl] = fmaf(c40[rr], vv[cl][rr], acc0[cl]);
                acc1[cl] = fmaf(c41[rr], vv[cl][rr], acc1[cl]);
                sv[cl]  += vv[cl][rr];
            }
        }
    }

    // j-sum across quads (lanes sharing the same col)
    #pragma unroll
    for (int cl = 0; cl < 4; ++cl) {
        acc0[cl] += __shfl_xor(acc0[cl], 16, 64);
        acc0[cl] += __shfl_xor(acc0[cl], 32, 64);
        acc1[cl] += __shfl_xor(acc1[cl], 16, 64);
        acc1[cl] += __shfl_xor(acc1[cl], 32, 64);
        sv[cl]   += __shfl_xor(sv[cl], 16, 64);
        sv[cl]   += __shfl_xor(sv[cl], 32, 64);
    }

    if (quad == 0) {
        int i0 = it4 * 4 + ip * 2;
        #pragma unroll
        for (int cl = 0; cl < 4; ++cl) {
            int cc = cth * 64 + cl * 16 + col;
            float bsv = attn_b2[cc] * sv[cl];
            out[((size_t)i0 * N_DIM + b) * OUT_DIM + cc]       = acc0[cl] + bsv;
            out[((size_t)(i0 + 1) * N_DIM + b) * OUT_DIM + cc] = acc1[cl] + bsv;
        }
    }
}

// ---------------------------------------------------------------------------
extern "C" void kernel_launch(void* const* d_in, const int* in_sizes, int n_in,
                              void* d_out, int out_size, void* d_ws, size_t ws_size,
                              hipStream_t stream)
{
    const float* x        = (const float*)d_in[0];
    const float* attn_w1  = (const float*)d_in[1];
    const float* attn_b1  = (const float*)d_in[2];
    const float* attn_w2  = (const float*)d_in[3];
    const float* attn_b2  = (const float*)d_in[4];
    const float* value_w1 = (const float*)d_in[5];
    const float* value_b1 = (const float*)d_in[6];
    const float* value_w2 = (const float*)d_in[7];
    const float* value_b2 = (const float*)d_in[8];
    float* out = (float*)d_out;

    // Workspace layout (floats): P 512K | Q 512K | Vt 512K | W2s(bf16) 16K
    float* ws  = (float*)d_ws;
    float* P   = ws;
    float* Q   = ws + 524288;
    float* Vt  = ws + 1048576;
    short* W2s = (short*)(ws + 1572864);

    k_pre<<<320, 256, 0, stream>>>(x, attn_w1, attn_b1, attn_w2,
                                   value_w1, value_b1, value_w2, value_b2,
                                   P, Q, Vt, W2s);
    k_main<<<1024, 256, 0, stream>>>(P, Q, Vt, W2s, attn_b2, out);
}

// Round 8
// 126.409 us; speedup vs baseline: 1.1453x; 1.1453x over previous
//
#include <hip/hip_runtime.h>
#include <hip/hip_bf16.h>

// Problem constants
#define L_DIM 128
#define N_DIM 32
#define C_DIM 128
#define K_DIM 128   // DIM_MLP
#define OUT_DIM 128

typedef __attribute__((ext_vector_type(8))) short short8;
typedef __attribute__((ext_vector_type(4))) float float4v;

static __device__ __forceinline__ short bf16_bits(float f) {
    __bf16 h = (__bf16)f;   // RNE
    return __builtin_bit_cast(short, h);
}

// async global->LDS, 16 B per lane, dest = wave-uniform base + lane*16
static __device__ __forceinline__ void gl_lds16(const float* g, float* l) {
    __builtin_amdgcn_global_load_lds(
        (const __attribute__((address_space(1))) unsigned int*)g,
        (__attribute__((address_space(3))) unsigned int*)l, 16, 0, 0);
}

// ---------------------------------------------------------------------------
// Kernel 1: precompute. 16 rows/block (r7 version, ~5 us, verified).
//   blocks 0..255  : b = bid>>3, i0 = (bid&7)*16.  P = x·W1a ; Q = x·W1b+b1 ;
//                    Vt[b][c][i] = relu(x·Vw1+vb1)·Vw2 + vb2 (transposed)
//   blocks 256..319: W2s = attn_w2 swizzled into bf16 MFMA B-fragment order
// ---------------------------------------------------------------------------
__global__ __launch_bounds__(256) void k_pre(
    const float* __restrict__ x,
    const float* __restrict__ attn_w1, const float* __restrict__ attn_b1,
    const float* __restrict__ attn_w2,
    const float* __restrict__ value_w1, const float* __restrict__ value_b1,
    const float* __restrict__ value_w2, const float* __restrict__ value_b2,
    float* __restrict__ P, float* __restrict__ Q, float* __restrict__ Vt,
    short* __restrict__ W2s)
{
    int bid = blockIdx.x;
    if (bid >= 256) {
        // W2 swizzle: element e = ((((ct*4+mi)*4+quad)*16+col)*8+idx)
        int e = (bid - 256) * 256 + threadIdx.x;      // 64*256 = 16384 elems
        int idx  = e & 7;
        int colr = (e >> 3) & 15;
        int quad = (e >> 7) & 3;
        int mi   = (e >> 9) & 3;
        int ct   = e >> 11;
        int k = quad * 8 + 32 * mi + idx;
        int c = ct * 16 + colr;
        W2s[e] = bf16_bits(attn_w2[k * OUT_DIM + c]);
        return;
    }

    __shared__ float xs[16][C_DIM];
    __shared__ float hvs[16][K_DIM];
    int tid = threadIdx.x;
    int b   = bid >> 3;             // batch (same for all 16 rows)
    int i0g = (bid & 7) * 16;       // first i

    {   // cooperative load of 16 x-rows (2048 floats, 8 per thread)
        int f = tid * 8;
        int row = f >> 7, c = f & 127;
        const float* xp = x + ((size_t)(i0g + row) * N_DIM + b) * C_DIM + c;
        *(float4v*)(&xs[row][c])     = *(const float4v*)xp;
        *(float4v*)(&xs[row][c + 4]) = *(const float4v*)(xp + 4);
    }
    __syncthreads();

    int ks   = tid & 127;      // output column k (or c)
    int half = tid >> 7;       // rows 0-7 vs 8-15

    float pacc[8] = {0,0,0,0,0,0,0,0};
    float qacc[8] = {0,0,0,0,0,0,0,0};
    float hacc[8] = {0,0,0,0,0,0,0,0};
    #pragma unroll 4
    for (int c = 0; c < C_DIM; ++c) {
        float wa = attn_w1[c * K_DIM + ks];
        float wb = attn_w1[(C_DIM + c) * K_DIM + ks];
        float wv = value_w1[c * K_DIM + ks];
        #pragma unroll
        for (int r = 0; r < 8; ++r) {
            float xr = xs[half * 8 + r][c];
            pacc[r] = fmaf(xr, wa, pacc[r]);
            qacc[r] = fmaf(xr, wb, qacc[r]);
            hacc[r] = fmaf(xr, wv, hacc[r]);
        }
    }
    float b1 = attn_b1[ks], vb1 = value_b1[ks];
    #pragma unroll
    for (int r = 0; r < 8; ++r) {
        int i = i0g + half * 8 + r;
        P[((size_t)b * L_DIM + i) * K_DIM + ks] = pacc[r];
        Q[((size_t)b * L_DIM + i) * K_DIM + ks] = qacc[r] + b1;
        hvs[half * 8 + r][ks] = fmaxf(hacc[r] + vb1, 0.f);
    }
    __syncthreads();

    float vacc[8] = {0,0,0,0,0,0,0,0};
    #pragma unroll 4
    for (int k = 0; k < K_DIM; ++k) {
        float w = value_w2[k * OUT_DIM + ks];
        #pragma unroll
        for (int r = 0; r < 8; ++r)
            vacc[r] = fmaf(hvs[half * 8 + r][k], w, vacc[r]);
    }
    float vb2 = value_b2[ks];
    float* vp = Vt + ((size_t)b * OUT_DIM + ks) * L_DIM + i0g + half * 8;
    float4v v0 = { vacc[0] + vb2, vacc[1] + vb2, vacc[2] + vb2, vacc[3] + vb2 };
    float4v v1 = { vacc[4] + vb2, vacc[5] + vb2, vacc[6] + vb2, vacc[7] + vb2 };
    *(float4v*)vp       = v0;
    *(float4v*)(vp + 4) = v1;
}

// ---------------------------------------------------------------------------
// Kernel 2: fused pairwise-MLP + j-reduce.  Counted-vmcnt edition (T3+T4+T5).
//   r6 post-mortem: __syncthreads drains vmcnt(0) -> every prefetch completed
//   inside its own round (m97 stall). This version uses RAW s_barrier with
//   s_waitcnt vmcnt(4) (never 0 mid-loop): the 4 newest DMAs (round r+2's
//   Q,V) stay in flight ACROSS the barrier. vmcnt precedes the barrier, so
//   every wave's own staging has landed before any wave passes -> cross-wave
//   LDS visibility is sound (m201 invariant).
//   Q AND V triple-buffered, staged 2 rounds ahead. setprio(1) around MFMA.
//   block = (b, it4 of 4 i's); 4 waves = 2 ipair x 2 cth (verified layout).
//   LDS 50 KB -> 3 blocks/CU (12 waves/CU).
// ---------------------------------------------------------------------------
__global__ __launch_bounds__(256)
void k_main(
    const float* __restrict__ P, const float* __restrict__ Q,
    const float* __restrict__ Vt,
    const short* __restrict__ W2s, const float* __restrict__ attn_b2,
    float* __restrict__ out)
{
    // LDS: Q 3x8KB | V 3x8KB | P 2KB  => 50 KB
    __shared__ float Q_lds[3][2048];   // granule (kc,j): floats [kc*64+j*4 ..]
    __shared__ float V_lds[3][2048];   // granule (c,s):  floats [c*16+s*4 ..]
    __shared__ float P_lds[512];

    int b    = blockIdx.x >> 5;
    int it4  = blockIdx.x & 31;
    int tid  = threadIdx.x;
    int wave = tid >> 6;
    int lane = tid & 63;
    int quad = lane >> 4;
    int col  = lane & 15;
    int ip   = wave >> 1;           // which i-pair
    int cth  = wave & 1;            // ct half: tiles cth*4 .. cth*4+3

    const float* Qbase = Q  + (size_t)b * L_DIM * K_DIM;
    const float* Vbase = Vt + (size_t)b * OUT_DIM * L_DIM;

    // B fragments: 4 ct tiles (verified swizzle, unchanged)
    short8 bfrag[4][4];
    const short8* w2p = (const short8*)W2s;
    #pragma unroll
    for (int cl = 0; cl < 4; ++cl)
        #pragma unroll
        for (int mi = 0; mi < 4; ++mi)
            bfrag[cl][mi] =
                w2p[(((cth * 4 + cl) * 4 + mi) * 4 + quad) * 16 + col];

    // per-lane DMA source offsets (float units), loop-invariant parts
    // Q: granule n = (t*4+wave)*64+lane: j=n&15, kc=n>>4
    //    src(jt) = (jt*16 + (n&15))*K_DIM + (n>>4)*4      [verified r6]
    // V: granule n: c=n>>2, s=n&3, ch=s^(c&3): src(jt) = c*L_DIM + jt*16+ch*4
    int qsrc[2], vsrc[2];
    #pragma unroll
    for (int t = 0; t < 2; ++t) {
        int n = (t * 4 + wave) * 64 + lane;
        qsrc[t] = (n & 15) * K_DIM + (n >> 4) * 4;
        int c = n >> 2, s = n & 3;
        vsrc[t] = c * L_DIM + ((s ^ (c & 3)) << 2);
    }

    auto stageQ = [&](int jt, int buf) {
        #pragma unroll
        for (int t = 0; t < 2; ++t)
            gl_lds16(Qbase + jt * 16 * K_DIM + qsrc[t],
                     &Q_lds[buf][(t * 4 + wave) * 256]);
    };
    auto stageV = [&](int jt, int buf) {
        #pragma unroll
        for (int t = 0; t < 2; ++t)
            gl_lds16(Vbase + jt * 16 + vsrc[t],
                     &V_lds[buf][(t * 4 + wave) * 256]);
    };

    // prologue: P FIRST (so vmcnt(4) covers it), then Q/V rounds 0 and 1.
    if (wave == 0) {
        const float* Pbase = P + ((size_t)b * L_DIM + it4 * 4) * K_DIM;
        gl_lds16(Pbase + lane * 4,       &P_lds[0]);
        gl_lds16(Pbase + 256 + lane * 4, &P_lds[256]);
    }
    stageQ(0, 0); stageV(0, 0);
    stageQ(1, 1); stageV(1, 1);
    // all but the newest 4 (Q1,V1) landed -> P,Q0,V0 visible after barrier
    asm volatile("s_waitcnt vmcnt(4)" ::: "memory");
    __builtin_amdgcn_sched_barrier(0);
    __builtin_amdgcn_s_barrier();

    float acc0[4] = {0.f, 0.f, 0.f, 0.f};
    float acc1[4] = {0.f, 0.f, 0.f, 0.f};
    float sv[4]   = {0.f, 0.f, 0.f, 0.f};
    int pofs = 0;      // opaque 0: keeps P reads in LDS (blocks reg-hoist)

    #pragma unroll
    for (int r = 0; r < 8; ++r) {
        asm volatile("" : "+v"(pofs));

        // ---- issue stage(r+2) early (T14): lands before barrier(r+1) ----
        if (r < 6) { stageQ(r + 2, (r + 2) % 3); stageV(r + 2, (r + 2) % 3); }

        // ---- build af(r) from Q_lds[r%3] + P_lds broadcast ----
        short8 af[2][4];
        {
            const float* qb = &Q_lds[r % 3][col * 4];
            const float* Pr = &P_lds[(ip * 2) * 128 + quad * 8 + pofs];
            #pragma unroll
            for (int ksl = 0; ksl < 4; ++ksl) {
                int kc0 = (ksl * 4 + quad) * 2;
                float4v q0 = *(const float4v*)(qb + kc0 * 64);
                float4v q1 = *(const float4v*)(qb + kc0 * 64 + 64);
                #pragma unroll
                for (int ii = 0; ii < 2; ++ii) {
                    const float* Pc = Pr + ii * 128 + ksl * 32;
                    float4v s0 = *(const float4v*)Pc + q0;
                    float4v s1 = *(const float4v*)(Pc + 4) + q1;
                    short8 a;
                    #pragma unroll
                    for (int t = 0; t < 4; ++t) {
                        a[t]     = bf16_bits(fmaxf(s0[t], 0.f));
                        a[t + 4] = bf16_bits(fmaxf(s1[t], 0.f));
                    }
                    af[ii][ksl] = a;
                }
            }
        }

        // ---- MFMA(r) + V-scale + fused Sv (setprio around MFMA, T5) ----
        __builtin_amdgcn_s_setprio(1);
        const float* Vc = &V_lds[r % 3][0];
        #pragma unroll
        for (int cl = 0; cl < 4; ++cl) {
            float4v c40 = {0.f, 0.f, 0.f, 0.f};
            float4v c41 = {0.f, 0.f, 0.f, 0.f};
            #pragma unroll
            for (int ksl = 0; ksl < 4; ++ksl) {
                c40 = __builtin_amdgcn_mfma_f32_16x16x32_bf16(
                        af[0][ksl], bfrag[cl][ksl], c40, 0, 0, 0);
                c41 = __builtin_amdgcn_mfma_f32_16x16x32_bf16(
                        af[1][ksl], bfrag[cl][ksl], c41, 0, 0, 0);
            }
            int cc = cth * 64 + cl * 16 + col;
            float4v vv = *(const float4v*)
                (Vc + cc * 16 + ((quad ^ (cc & 3)) << 2));
            #pragma unroll
            for (int rr = 0; rr < 4; ++rr) {
                acc0[cl] = fmaf(c40[rr], vv[rr], acc0[cl]);
                acc1[cl] = fmaf(c41[rr], vv[rr], acc1[cl]);
                sv[cl]  += vv[rr];
            }
        }
        __builtin_amdgcn_s_setprio(0);

        // ---- counted-vmcnt barrier: round r+1's data landed, round r+2's
        //      4 loads stay IN FLIGHT across the barrier (T4) ----
        if (r < 7) {
            if (r < 6) asm volatile("s_waitcnt vmcnt(4)" ::: "memory");
            else       asm volatile("s_waitcnt vmcnt(0)" ::: "memory");
            __builtin_amdgcn_sched_barrier(0);
            __builtin_amdgcn_s_barrier();
        }
    }

    // j-sum across quads (lanes sharing the same col)
    #pragma unroll
    for (int cl = 0; cl < 4; ++cl) {
        acc0[cl] += __shfl_xor(acc0[cl], 16, 64);
        acc0[cl] += __shfl_xor(acc0[cl], 32, 64);
        acc1[cl] += __shfl_xor(acc1[cl], 16, 64);
        acc1[cl] += __shfl_xor(acc1[cl], 32, 64);
        sv[cl]   += __shfl_xor(sv[cl], 16, 64);
        sv[cl]   += __shfl_xor(sv[cl], 32, 64);
    }

    if (quad == 0) {
        int i0 = it4 * 4 + ip * 2;
        #pragma unroll
        for (int cl = 0; cl < 4; ++cl) {
            int cc = cth * 64 + cl * 16 + col;
            float bsv = attn_b2[cc] * sv[cl];
            out[((size_t)i0 * N_DIM + b) * OUT_DIM + cc]       = acc0[cl] + bsv;
            out[((size_t)(i0 + 1) * N_DIM + b) * OUT_DIM + cc] = acc1[cl] + bsv;
        }
    }
}

// ---------------------------------------------------------------------------
extern "C" void kernel_launch(void* const* d_in, const int* in_sizes, int n_in,
                              void* d_out, int out_size, void* d_ws, size_t ws_size,
                              hipStream_t stream)
{
    const float* x        = (const float*)d_in[0];
    const float* attn_w1  = (const float*)d_in[1];
    const float* attn_b1  = (const float*)d_in[2];
    const float* attn_w2  = (const float*)d_in[3];
    const float* attn_b2  = (const float*)d_in[4];
    const float* value_w1 = (const float*)d_in[5];
    const float* value_b1 = (const float*)d_in[6];
    const float* value_w2 = (const float*)d_in[7];
    const float* value_b2 = (const float*)d_in[8];
    float* out = (float*)d_out;

    // Workspace layout (floats): P 512K | Q 512K | Vt 512K | W2s(bf16) 16K
    float* ws  = (float*)d_ws;
    float* P   = ws;
    float* Q   = ws + 524288;
    float* Vt  = ws + 1048576;
    short* W2s = (short*)(ws + 1572864);

    k_pre<<<320, 256, 0, stream>>>(x, attn_w1, attn_b1, attn_w2,
                                   value_w1, value_b1, value_w2, value_b2,
                                   P, Q, Vt, W2s);
    k_main<<<1024, 256, 0, stream>>>(P, Q, Vt, W2s, attn_b2, out);
}

// Round 9
// 126.312 us; speedup vs baseline: 1.1462x; 1.0008x over previous
//
#include <hip/hip_runtime.h>
#include <hip/hip_bf16.h>

// Problem constants
#define L_DIM 128
#define N_DIM 32
#define C_DIM 128
#define K_DIM 128   // DIM_MLP
#define OUT_DIM 128

typedef __attribute__((ext_vector_type(8))) short short8;
typedef __attribute__((ext_vector_type(4))) float float4v;

static __device__ __forceinline__ short bf16_bits(float f) {
    __bf16 h = (__bf16)f;   // RNE
    return __builtin_bit_cast(short, h);
}

// async global->LDS, 16 B per lane, dest = wave-uniform base + lane*16
static __device__ __forceinline__ void gl_lds16(const float* g, float* l) {
    __builtin_amdgcn_global_load_lds(
        (const __attribute__((address_space(1))) unsigned int*)g,
        (__attribute__((address_space(3))) unsigned int*)l, 16, 0, 0);
}

// ---------------------------------------------------------------------------
// Kernel 1: precompute. 16 rows/block (verified r7/r8 version).
//   blocks 0..255  : b = bid>>3, i0 = (bid&7)*16.  P = x·W1a ; Q = x·W1b+b1 ;
//                    Vt[b][c][i] = relu(x·Vw1+vb1)·Vw2 + vb2 (transposed)
//   blocks 256..319: W2s = attn_w2 swizzled into bf16 MFMA B-fragment order
// ---------------------------------------------------------------------------
__global__ __launch_bounds__(256) void k_pre(
    const float* __restrict__ x,
    const float* __restrict__ attn_w1, const float* __restrict__ attn_b1,
    const float* __restrict__ attn_w2,
    const float* __restrict__ value_w1, const float* __restrict__ value_b1,
    const float* __restrict__ value_w2, const float* __restrict__ value_b2,
    float* __restrict__ P, float* __restrict__ Q, float* __restrict__ Vt,
    short* __restrict__ W2s)
{
    int bid = blockIdx.x;
    if (bid >= 256) {
        // W2 swizzle: element e = ((((ct*4+mi)*4+quad)*16+col)*8+idx)
        int e = (bid - 256) * 256 + threadIdx.x;      // 64*256 = 16384 elems
        int idx  = e & 7;
        int colr = (e >> 3) & 15;
        int quad = (e >> 7) & 3;
        int mi   = (e >> 9) & 3;
        int ct   = e >> 11;
        int k = quad * 8 + 32 * mi + idx;
        int c = ct * 16 + colr;
        W2s[e] = bf16_bits(attn_w2[k * OUT_DIM + c]);
        return;
    }

    __shared__ float xs[16][C_DIM];
    __shared__ float hvs[16][K_DIM];
    int tid = threadIdx.x;
    int b   = bid >> 3;             // batch (same for all 16 rows)
    int i0g = (bid & 7) * 16;       // first i

    {   // cooperative load of 16 x-rows (2048 floats, 8 per thread)
        int f = tid * 8;
        int row = f >> 7, c = f & 127;
        const float* xp = x + ((size_t)(i0g + row) * N_DIM + b) * C_DIM + c;
        *(float4v*)(&xs[row][c])     = *(const float4v*)xp;
        *(float4v*)(&xs[row][c + 4]) = *(const float4v*)(xp + 4);
    }
    __syncthreads();

    int ks   = tid & 127;      // output column k (or c)
    int half = tid >> 7;       // rows 0-7 vs 8-15

    float pacc[8] = {0,0,0,0,0,0,0,0};
    float qacc[8] = {0,0,0,0,0,0,0,0};
    float hacc[8] = {0,0,0,0,0,0,0,0};
    #pragma unroll 4
    for (int c = 0; c < C_DIM; ++c) {
        float wa = attn_w1[c * K_DIM + ks];
        float wb = attn_w1[(C_DIM + c) * K_DIM + ks];
        float wv = value_w1[c * K_DIM + ks];
        #pragma unroll
        for (int r = 0; r < 8; ++r) {
            float xr = xs[half * 8 + r][c];
            pacc[r] = fmaf(xr, wa, pacc[r]);
            qacc[r] = fmaf(xr, wb, qacc[r]);
            hacc[r] = fmaf(xr, wv, hacc[r]);
        }
    }
    float b1 = attn_b1[ks], vb1 = value_b1[ks];
    #pragma unroll
    for (int r = 0; r < 8; ++r) {
        int i = i0g + half * 8 + r;
        P[((size_t)b * L_DIM + i) * K_DIM + ks] = pacc[r];
        Q[((size_t)b * L_DIM + i) * K_DIM + ks] = qacc[r] + b1;
        hvs[half * 8 + r][ks] = fmaxf(hacc[r] + vb1, 0.f);
    }
    __syncthreads();

    float vacc[8] = {0,0,0,0,0,0,0,0};
    #pragma unroll 4
    for (int k = 0; k < K_DIM; ++k) {
        float w = value_w2[k * OUT_DIM + ks];
        #pragma unroll
        for (int r = 0; r < 8; ++r)
            vacc[r] = fmaf(hvs[half * 8 + r][k], w, vacc[r]);
    }
    float vb2 = value_b2[ks];
    float* vp = Vt + ((size_t)b * OUT_DIM + ks) * L_DIM + i0g + half * 8;
    float4v v0 = { vacc[0] + vb2, vacc[1] + vb2, vacc[2] + vb2, vacc[3] + vb2 };
    float4v v1 = { vacc[4] + vb2, vacc[5] + vb2, vacc[6] + vb2, vacc[7] + vb2 };
    *(float4v*)vp       = v0;
    *(float4v*)(vp + 4) = v1;
}

// ---------------------------------------------------------------------------
// Kernel 2: fused pairwise-MLP + j-reduce.  Composite edition:
//   r8's DMA + counted-vmcnt + raw-barrier + setprio schedule, with P in
//   REGISTERS (r4-verified pf pattern). LDS-read pipe accounting (r8 post-
//   mortem): P-in-LDS cost 16 of 28 ds_read_b128/thread-round (~10 us of
//   per-CU LDS pipe) -> deleted. Per thread-round now: Q 8 + V 4 reads.
//   block = (b, it4 of 4 i's); 4 waves = 2 ipair x 2 cth (verified layout).
//   LDS 48 KB; regs ~200 -> 2 waves/SIMD (occupancy proven non-binding r2/r5).
// ---------------------------------------------------------------------------
__global__ __launch_bounds__(256)
void k_main(
    const float* __restrict__ P, const float* __restrict__ Q,
    const float* __restrict__ Vt,
    const short* __restrict__ W2s, const float* __restrict__ attn_b2,
    float* __restrict__ out)
{
    // LDS: Q 3x8KB | V 3x8KB  => 48 KB
    __shared__ float Q_lds[3][2048];   // granule (kc,j): floats [kc*64+j*4 ..]
    __shared__ float V_lds[3][2048];   // granule (c,s):  floats [c*16+s*4 ..]

    int b    = blockIdx.x >> 5;
    int it4  = blockIdx.x & 31;
    int tid  = threadIdx.x;
    int wave = tid >> 6;
    int lane = tid & 63;
    int quad = lane >> 4;
    int col  = lane & 15;
    int ip   = wave >> 1;           // which i-pair
    int cth  = wave & 1;            // ct half: tiles cth*4 .. cth*4+3
    int i0   = it4 * 4 + ip * 2;

    const float* Qbase = Q  + (size_t)b * L_DIM * K_DIM;
    const float* Vbase = Vt + (size_t)b * OUT_DIM * L_DIM;

    // B fragments: 4 ct tiles (verified swizzle, unchanged)
    short8 bfrag[4][4];
    const short8* w2p = (const short8*)W2s;
    #pragma unroll
    for (int cl = 0; cl < 4; ++cl)
        #pragma unroll
        for (int mi = 0; mi < 4; ++mi)
            bfrag[cl][mi] =
                w2p[(((cth * 4 + cl) * 4 + mi) * 4 + quad) * 16 + col];

    // P fragments for BOTH i's, register-resident (r4-verified pattern).
    // lane needs P[i][k], k = ksl*32 + quad*8 + t  (t=0..7)
    float4v pf[2][4][2];
    #pragma unroll
    for (int ii = 0; ii < 2; ++ii) {
        const float* Pp = P + ((size_t)b * L_DIM + i0 + ii) * K_DIM + quad * 8;
        #pragma unroll
        for (int ksl = 0; ksl < 4; ++ksl) {
            pf[ii][ksl][0] = *(const float4v*)(Pp + ksl * 32);
            pf[ii][ksl][1] = *(const float4v*)(Pp + ksl * 32 + 4);
        }
    }

    // per-lane DMA source offsets (float units), loop-invariant parts
    // Q: granule n = (t*4+wave)*64+lane: j=n&15, kc=n>>4
    //    src(jt) = (jt*16 + (n&15))*K_DIM + (n>>4)*4      [verified r6/r8]
    // V: granule n: c=n>>2, s=n&3, ch=s^(c&3): src(jt) = c*L_DIM + jt*16+ch*4
    int qsrc[2], vsrc[2];
    #pragma unroll
    for (int t = 0; t < 2; ++t) {
        int n = (t * 4 + wave) * 64 + lane;
        qsrc[t] = (n & 15) * K_DIM + (n >> 4) * 4;
        int c = n >> 2, s = n & 3;
        vsrc[t] = c * L_DIM + ((s ^ (c & 3)) << 2);
    }

    auto stageQ = [&](int jt, int buf) {
        #pragma unroll
        for (int t = 0; t < 2; ++t)
            gl_lds16(Qbase + jt * 16 * K_DIM + qsrc[t],
                     &Q_lds[buf][(t * 4 + wave) * 256]);
    };
    auto stageV = [&](int jt, int buf) {
        #pragma unroll
        for (int t = 0; t < 2; ++t)
            gl_lds16(Vbase + jt * 16 + vsrc[t],
                     &V_lds[buf][(t * 4 + wave) * 256]);
    };

    // prologue: bfrag+pf global loads were issued above (oldest in queue),
    // then rounds 0 and 1. vmcnt(4) leaves only stage(1) in flight =>
    // bfrag, pf, Q0, V0 all landed before any wave crosses the barrier.
    stageQ(0, 0); stageV(0, 0);
    stageQ(1, 1); stageV(1, 1);
    asm volatile("s_waitcnt vmcnt(4)" ::: "memory");
    __builtin_amdgcn_sched_barrier(0);
    __builtin_amdgcn_s_barrier();

    float acc0[4] = {0.f, 0.f, 0.f, 0.f};
    float acc1[4] = {0.f, 0.f, 0.f, 0.f};
    float sv[4]   = {0.f, 0.f, 0.f, 0.f};

    #pragma unroll
    for (int r = 0; r < 8; ++r) {
        // ---- issue stage(r+2) early: writes buf (r+2)%3 == (r-1)%3, whose
        //      readers all finished before the barrier we just crossed ----
        if (r < 6) { stageQ(r + 2, (r + 2) % 3); stageV(r + 2, (r + 2) % 3); }

        // ---- build af(r) from Q_lds[r%3] + register P ----
        short8 af[2][4];
        {
            const float* qb = &Q_lds[r % 3][col * 4];
            #pragma unroll
            for (int ksl = 0; ksl < 4; ++ksl) {
                int kc0 = (ksl * 4 + quad) * 2;
                float4v q0 = *(const float4v*)(qb + kc0 * 64);
                float4v q1 = *(const float4v*)(qb + kc0 * 64 + 64);
                #pragma unroll
                for (int ii = 0; ii < 2; ++ii) {
                    float4v s0 = pf[ii][ksl][0] + q0;
                    float4v s1 = pf[ii][ksl][1] + q1;
                    short8 a;
                    #pragma unroll
                    for (int t = 0; t < 4; ++t) {
                        a[t]     = bf16_bits(fmaxf(s0[t], 0.f));
                        a[t + 4] = bf16_bits(fmaxf(s1[t], 0.f));
                    }
                    af[ii][ksl] = a;
                }
            }
        }

        // ---- MFMA(r) + V-scale + fused Sv (setprio around MFMA) ----
        __builtin_amdgcn_s_setprio(1);
        const float* Vc = &V_lds[r % 3][0];
        #pragma unroll
        for (int cl = 0; cl < 4; ++cl) {
            float4v c40 = {0.f, 0.f, 0.f, 0.f};
            float4v c41 = {0.f, 0.f, 0.f, 0.f};
            #pragma unroll
            for (int ksl = 0; ksl < 4; ++ksl) {
                c40 = __builtin_amdgcn_mfma_f32_16x16x32_bf16(
                        af[0][ksl], bfrag[cl][ksl], c40, 0, 0, 0);
                c41 = __builtin_amdgcn_mfma_f32_16x16x32_bf16(
                        af[1][ksl], bfrag[cl][ksl], c41, 0, 0, 0);
            }
            int cc = cth * 64 + cl * 16 + col;
            float4v vv = *(const float4v*)
                (Vc + cc * 16 + ((quad ^ (cc & 3)) << 2));
            #pragma unroll
            for (int rr = 0; rr < 4; ++rr) {
                acc0[cl] = fmaf(c40[rr], vv[rr], acc0[cl]);
                acc1[cl] = fmaf(c41[rr], vv[rr], acc1[cl]);
                sv[cl]  += vv[rr];
            }
        }
        __builtin_amdgcn_s_setprio(0);

        // ---- counted-vmcnt barrier: round r+1's data landed, round r+2's
        //      4 loads stay IN FLIGHT across the barrier ----
        if (r < 7) {
            if (r < 6) asm volatile("s_waitcnt vmcnt(4)" ::: "memory");
            else       asm volatile("s_waitcnt vmcnt(0)" ::: "memory");
            __builtin_amdgcn_sched_barrier(0);
            __builtin_amdgcn_s_barrier();
        }
    }

    // j-sum across quads (lanes sharing the same col)
    #pragma unroll
    for (int cl = 0; cl < 4; ++cl) {
        acc0[cl] += __shfl_xor(acc0[cl], 16, 64);
        acc0[cl] += __shfl_xor(acc0[cl], 32, 64);
        acc1[cl] += __shfl_xor(acc1[cl], 16, 64);
        acc1[cl] += __shfl_xor(acc1[cl], 32, 64);
        sv[cl]   += __shfl_xor(sv[cl], 16, 64);
        sv[cl]   += __shfl_xor(sv[cl], 32, 64);
    }

    if (quad == 0) {
        #pragma unroll
        for (int cl = 0; cl < 4; ++cl) {
            int cc = cth * 64 + cl * 16 + col;
            float bsv = attn_b2[cc] * sv[cl];
            out[((size_t)i0 * N_DIM + b) * OUT_DIM + cc]       = acc0[cl] + bsv;
            out[((size_t)(i0 + 1) * N_DIM + b) * OUT_DIM + cc] = acc1[cl] + bsv;
        }
    }
}

// ---------------------------------------------------------------------------
extern "C" void kernel_launch(void* const* d_in, const int* in_sizes, int n_in,
                              void* d_out, int out_size, void* d_ws, size_t ws_size,
                              hipStream_t stream)
{
    const float* x        = (const float*)d_in[0];
    const float* attn_w1  = (const float*)d_in[1];
    const float* attn_b1  = (const float*)d_in[2];
    const float* attn_w2  = (const float*)d_in[3];
    const float* attn_b2  = (const float*)d_in[4];
    const float* value_w1 = (const float*)d_in[5];
    const float* value_b1 = (const float*)d_in[6];
    const float* value_w2 = (const float*)d_in[7];
    const float* value_b2 = (const float*)d_in[8];
    float* out = (float*)d_out;

    // Workspace layout (floats): P 512K | Q 512K | Vt 512K | W2s(bf16) 16K
    float* ws  = (float*)d_ws;
    float* P   = ws;
    float* Q   = ws + 524288;
    float* Vt  = ws + 1048576;
    short* W2s = (short*)(ws + 1572864);

    k_pre<<<320, 256, 0, stream>>>(x, attn_w1, attn_b1, attn_w2,
                                   value_w1, value_b1, value_w2, value_b2,
                                   P, Q, Vt, W2s);
    k_main<<<1024, 256, 0, stream>>>(P, Q, Vt, W2s, attn_b2, out);
}